// Round 9
// baseline (341.539 us; speedup 1.0000x reference)
//
#include <hip/hip_runtime.h>
#include <math.h>

// Problem constants (B, N, L, D) from the reference setup_inputs().
#define BSZ 64
#define NN  128
#define LL  64
#define DD  768
#define NEGV (-9e9f)

#define TQ (BSZ * NN * DD / 4)   // text float4 count  = 1572864
#define IQ (BSZ * LL * DD / 4)   // image float4 count =  786432

typedef _Float16 f16x8 __attribute__((ext_vector_type(8)));   // 8 f16 = 4 VGPRs
typedef __attribute__((ext_vector_type(16))) float f32x16;    // MFMA 32x32 accum

// async 16B global -> LDS (dest = wave-uniform base + lane*16)
__device__ __forceinline__ void gl_lds16(const void* g, void* l) {
    __builtin_amdgcn_global_load_lds(
        (const __attribute__((address_space(1))) void*)g,
        (__attribute__((address_space(3))) void*)l, 16, 0, 0);
}

// ---------------------------------------------------------------------------
// Kernel 0: fp32 -> fp16 (RTN). Error 2^-11 relative; N(0,1) inputs.
// ---------------------------------------------------------------------------
__global__ __launch_bounds__(256) void k_prep(
    const float4* __restrict__ t4, const float4* __restrict__ g4,
    ushort4* __restrict__ A, ushort4* __restrict__ B)
{
    int id = blockIdx.x * 256 + threadIdx.x;
    const float4* src; ushort4* dst; int idx;
    if (id < TQ) { src = t4; dst = A; idx = id; }
    else         { src = g4; dst = B; idx = id - TQ; }
    float4 x = src[idx];
    _Float16 h0 = (_Float16)x.x, h1 = (_Float16)x.y;
    _Float16 h2 = (_Float16)x.z, h3 = (_Float16)x.w;
    ushort4 o;
    o.x = __builtin_bit_cast(unsigned short, h0);
    o.y = __builtin_bit_cast(unsigned short, h1);
    o.z = __builtin_bit_cast(unsigned short, h2);
    o.w = __builtin_bit_cast(unsigned short, h3);
    dst[idx] = o;
}

// ---------------------------------------------------------------------------
// Stage one BK=64 chunk for a 256x256 tile (A 32 KB + B 32 KB) into LDS,
// k8-major layout (conflict-free ds_read_b128):
//   slot = k8*256 + r   (k8 in [0,8) = 8-f16 k-slices, r = row/col in [0,256))
// global_load_lds dest = wave-uniform base + lane*16; global src is per-lane,
// so src = r*DD + k0 + k8*8 realizes the k8-major layout with linear dest.
// 512 threads x 4 calls x (A,B) = 4096 x 16B slots = 64 KB.
// ---------------------------------------------------------------------------
__device__ __forceinline__ void stage_chunk(
    const unsigned short* __restrict__ pa, const unsigned short* __restrict__ pb,
    int k0, char* buf, int wave, int lane)
{
#pragma unroll
    for (int cc = 0; cc < 4; ++cc) {
        int s  = cc * 512 + wave * 64 + lane;   // 0..2047
        int k8 = s >> 8, r = s & 255;
        gl_lds16(pa + (size_t)r * DD + k0 + k8 * 8, buf + cc * 8192 + wave * 1024);
        gl_lds16(pb + (size_t)r * DD + k0 + k8 * 8, buf + 32768 + cc * 8192 + wave * 1024);
    }
}

// ---------------------------------------------------------------------------
// Kernel 1 (R9 rewrite): 256x256 tile GEMM over the flattened pairwise matrix
// C[8192][4096] = text_all @ image_all^T.  Grid 32x16 = 512 blocks, 512 thr =
// 8 waves (2M x 4N).  Each wave owns rows wm*128..+128 (= ONE text i) and
// cols wn*64..+64 (= ONE image j) -> the per-(i,j) masked softmax epilogue is
// fully in-register (shfl reductions), no C LDS round-trip.
// MFMA 32x32x16 f16: A/B operand row=lane&31, k=(lane>>5)*8+[0..8) (analogy
// of the verified 16x16 layout); C/D col=lane&31,
// row=(reg&3)+8*(reg>>2)+4*(lane>>5) (guide-verified).
// K-loop: proven 2-phase structure (stage next / compute cur / barrier),
// BK=64 = 4 K-steps, 12 chunks, double-buffered 128 KB LDS.
// Spill discipline (R3/R6): launch_bounds(512,2) -> 256-reg cap, demand ~190.
// ---------------------------------------------------------------------------
__global__ __launch_bounds__(512, 2) void k_scores(
    const unsigned short* __restrict__ A, const unsigned short* __restrict__ B,
    const int* __restrict__ tmask, const int* __restrict__ imask,
    float* __restrict__ S, float* __restrict__ W)
{
    __shared__ __align__(16) char smem[131072];   // [2][A 32KB | B 32KB]
    char* buf0 = smem;
    char* buf1 = smem + 65536;

    // 4x4 block-group swizzle for L2 locality
    const int bid = blockIdx.x;            // 0..511
    const int grp = bid >> 4, idx = bid & 15;
    const int tm = (grp >> 2) * 4 + (idx >> 2);   // 0..31 (M-tile)
    const int tn = (grp & 3) * 4 + (idx & 3);     // 0..15 (N-tile)

    const int tid  = threadIdx.x;
    const int wave = tid >> 6;     // 0..7
    const int lane = tid & 63;
    const int l31  = lane & 31;
    const int hi   = lane >> 5;
    const int wm   = wave >> 2;    // 0..1: rows wm*128 (= i = tm*2+wm)
    const int wn   = wave & 3;     // 0..3: cols wn*64  (= j = tn*4+wn)

    const unsigned short* pa = A + (size_t)tm * 256 * DD;
    const unsigned short* pb = B + (size_t)tn * 256 * DD;

    const f32x16 zf16 = {0.f,0.f,0.f,0.f,0.f,0.f,0.f,0.f,
                         0.f,0.f,0.f,0.f,0.f,0.f,0.f,0.f};
    f32x16 acc[4][2];
#pragma unroll
    for (int mt = 0; mt < 4; ++mt)
#pragma unroll
        for (int nt = 0; nt < 2; ++nt) acc[mt][nt] = zf16;

    stage_chunk(pa, pb, 0, buf0, wave, lane);
    __syncthreads();

    for (int c = 0; c < 12; ++c) {
        char* cur = (c & 1) ? buf1 : buf0;
        if (c + 1 < 12)
            stage_chunk(pa, pb, (c + 1) << 6, (c & 1) ? buf0 : buf1, wave, lane);
#pragma unroll
        for (int s16 = 0; s16 < 4; ++s16) {
            const int k8 = s16 * 2 + hi;
            f16x8 af[4], bf[2];
#pragma unroll
            for (int mt = 0; mt < 4; ++mt)
                af[mt] = *(const f16x8*)(cur + ((k8 << 8) + wm * 128 + mt * 32 + l31) * 16);
#pragma unroll
            for (int nt = 0; nt < 2; ++nt)
                bf[nt] = *(const f16x8*)(cur + 32768 + ((k8 << 8) + wn * 64 + nt * 32 + l31) * 16);
#pragma unroll
            for (int mt = 0; mt < 4; ++mt)
#pragma unroll
                for (int nt = 0; nt < 2; ++nt)
                    acc[mt][nt] = __builtin_amdgcn_mfma_f32_32x32x16_f16(
                        af[mt], bf[nt], acc[mt][nt], 0, 0, 0);
        }
        __syncthreads();
    }

    // ---- masks into (dead) stage LDS: tmi [0..255], imj [256..511] ----
    float* msk   = (float*)smem;
    float* rowmL = (float*)smem + 512;   // diag row stats: [wm*128 + n]
    float* rowsL = (float*)smem + 768;
    if (tid < 256) msk[tid] = tmask[tm * 256 + tid] ? 1.f : 0.f;
    else           msk[tid] = imask[tn * 256 + (tid - 256)] ? 1.f : 0.f;
    __syncthreads();

    const float imv0 = msk[256 + wn * 64 + l31];        // col mask, nt=0
    const float imv1 = msk[256 + wn * 64 + 32 + l31];   // col mask, nt=1

    // ---- mask acc in place: vm = (tmask && imask && v!=0) ? v : NEG ----
    // C/D: col = l31 (+nt*32), row_local = (q&3) + 8*(q>>2) + 4*hi (+mt*32)
#pragma unroll
    for (int mt = 0; mt < 4; ++mt) {
#pragma unroll
        for (int q = 0; q < 16; ++q) {
            int rl = (q & 3) + 8 * (q >> 2) + 4 * hi;
            float tmv = msk[wm * 128 + mt * 32 + rl];
            float v0 = acc[mt][0][q];
            float v1 = acc[mt][1][q];
            acc[mt][0][q] = (tmv != 0.f && imv0 != 0.f && v0 != 0.f) ? v0 : NEGV;
            acc[mt][1][q] = (tmv != 0.f && imv1 != 0.f && v1 != 0.f) ? v1 : NEGV;
        }
    }

    const bool diagw = (tm * 2 + wm) == (tn * 4 + wn);

    // ---- row softmax (over the wave's 64 cols), fully in-register ----
    // Row r lives in one 32-lane half (hi = (r>>2)&1): shfl_xor 1..16 reduces.
    float srow = 0.f;
#pragma unroll
    for (int mt = 0; mt < 4; ++mt) {
#pragma unroll
        for (int q = 0; q < 16; ++q) {
            float v0 = acc[mt][0][q], v1 = acc[mt][1][q];
            float m = fmaxf(v0, v1);
#pragma unroll
            for (int d = 1; d <= 16; d <<= 1) m = fmaxf(m, __shfl_xor(m, d));
            float e0 = __expf(v0 - m), e1 = __expf(v1 - m);
            float ss = e0 + e1;
            float ws = imv0 * e0 * v0 + imv1 * e1 * v1;
#pragma unroll
            for (int d = 1; d <= 16; d <<= 1) {
                ss += __shfl_xor(ss, d);
                ws += __shfl_xor(ws, d);
            }
            int rl = (q & 3) + 8 * (q >> 2) + 4 * hi;
            float tmv = msk[wm * 128 + mt * 32 + rl];
            srow += tmv * (ws / ss);
            if (diagw && l31 == 0) {          // stash row stats for W
                rowmL[wm * 128 + mt * 32 + rl] = m;
                rowsL[wm * 128 + mt * 32 + rl] = ss;
            }
        }
    }
    srow += __shfl_xor(srow, 32);             // combine the two row-halves

    // ---- col softmax (over the wave's 128 rows) ----
    // Column c: 64 values in this lane (4mt x 16q) + 64 in lane^32.
    float scol = 0.f;
#pragma unroll
    for (int nt = 0; nt < 2; ++nt) {
        float m = -INFINITY;
#pragma unroll
        for (int mt = 0; mt < 4; ++mt)
#pragma unroll
            for (int q = 0; q < 16; ++q) m = fmaxf(m, acc[mt][nt][q]);
        m = fmaxf(m, __shfl_xor(m, 32));
        float ss = 0.f, ws = 0.f;
#pragma unroll
        for (int mt = 0; mt < 4; ++mt)
#pragma unroll
            for (int q = 0; q < 16; ++q) {
                int rl = (q & 3) + 8 * (q >> 2) + 4 * hi;
                float tmv = msk[wm * 128 + mt * 32 + rl];
                float v = acc[mt][nt][q];
                float e = __expf(v - m);
                ss += e;
                ws += tmv * e * v;
            }
        ss += __shfl_xor(ss, 32);
        ws += __shfl_xor(ws, 32);
        float imv = nt ? imv1 : imv0;
        scol += imv * (ws / ss);
    }
    // sum over the wave's 64 columns (each column duplicated in lane pairs)
#pragma unroll
    for (int d = 1; d <= 32; d <<= 1) scol += __shfl_xor(scol, d);
    scol *= 0.5f;

    if (lane == 0)
        S[(tm * 2 + wm) * BSZ + (tn * 4 + wn)] = (srow + scol) / (float)NN;

    __syncthreads();   // rowmL/rowsL visible wave-wide before W pass

    // ---- diagonal W (64 waves grid-wide): W[i][l][n] = exp(vm-m)/ssum ----
    if (diagw) {
        float* Wb = W + (size_t)(tm * 2 + wm) * LL * NN;
#pragma unroll
        for (int nt = 0; nt < 2; ++nt) {
            int col = wn * 64 + nt * 32 + l31;   // this lane's l (j-local)
#pragma unroll
            for (int mt = 0; mt < 4; ++mt) {
#pragma unroll
                for (int qq = 0; qq < 4; ++qq) {
                    int n0 = mt * 32 + 8 * qq + 4 * hi;   // 4 consecutive n
                    float4 w;
                    w.x = __expf(acc[mt][nt][qq * 4 + 0] - rowmL[wm * 128 + n0 + 0]) / rowsL[wm * 128 + n0 + 0];
                    w.y = __expf(acc[mt][nt][qq * 4 + 1] - rowmL[wm * 128 + n0 + 1]) / rowsL[wm * 128 + n0 + 1];
                    w.z = __expf(acc[mt][nt][qq * 4 + 2] - rowmL[wm * 128 + n0 + 2]) / rowsL[wm * 128 + n0 + 2];
                    w.w = __expf(acc[mt][nt][qq * 4 + 3] - rowmL[wm * 128 + n0 + 3]) / rowsL[wm * 128 + n0 + 3];
                    *(float4*)(Wb + ((size_t)col & 63) * NN + n0) = w;
                }
            }
        }
    }
}

// ---------------------------------------------------------------------------
// Kernel 2: text_emb_i2s[b,n,d] = sum_l W[b][l][n] * img[b][l][d]
// Grid: (64 b, 3 d-chunks of 256, 8 n-groups of 16).  W chunk staged in LDS.
// k_loss fused into the tail of block (0,0,0).
// ---------------------------------------------------------------------------
__global__ __launch_bounds__(256) void k_i2s(
    const float* __restrict__ W, const float* __restrict__ img,
    const float* __restrict__ S, float* __restrict__ out)
{
    __shared__ float Ws[LL][16];   // 4 KB
    const int b  = blockIdx.x;
    const int ng = blockIdx.z * 16;
    const int d  = blockIdx.y * 256 + threadIdx.x;
    const float* Wb = W + (size_t)b * LL * NN;

    {   // stage W[l][ng..ng+15]: 1024 floats, 4 per thread
        int t4 = threadIdx.x * 4;
        int l = t4 >> 4, noff = t4 & 15;
        float4 w = *(const float4*)(Wb + (size_t)l * NN + ng + noff);
        Ws[l][noff + 0] = w.x; Ws[l][noff + 1] = w.y;
        Ws[l][noff + 2] = w.z; Ws[l][noff + 3] = w.w;
    }
    __syncthreads();

    const float* ib = img + (size_t)b * LL * DD;
    float* ob = out + 1 + (size_t)b * NN * DD + (size_t)ng * DD;  // slot 0 = loss

    float acc[16];
#pragma unroll
    for (int q = 0; q < 16; q++) acc[q] = 0.f;
    for (int l = 0; l < LL; l++) {
        float g = ib[(size_t)l * DD + d];
#pragma unroll
        for (int q = 0; q < 16; q++)
            acc[q] = fmaf(Ws[l][q], g, acc[q]);   // Ws read is broadcast
    }
#pragma unroll
    for (int q = 0; q < 16; q++)
        ob[(size_t)q * DD + d] = acc[q];

    // fused loss: loss = -sum_i( 2*S[i,i] - lse_row_i(S) - lse_col_i(S) ) / B
    if (blockIdx.x == 0 && blockIdx.y == 0 && blockIdx.z == 0 && threadIdx.x < 64) {
        const int t = threadIdx.x;  // 0..63
        float diag = S[t * BSZ + t];
        float m1 = -INFINITY, m2 = -INFINITY;
        for (int jj = 0; jj < BSZ; jj++) {
            m1 = fmaxf(m1, S[t * BSZ + jj]);
            m2 = fmaxf(m2, S[jj * BSZ + t]);
        }
        float s1 = 0.f, s2 = 0.f;
        for (int jj = 0; jj < BSZ; jj++) {
            s1 += __expf(S[t * BSZ + jj] - m1);
            s2 += __expf(S[jj * BSZ + t] - m2);
        }
        float p = 2.f * diag - (m1 + logf(s1)) - (m2 + logf(s2));
#pragma unroll
        for (int off = 32; off; off >>= 1) p += __shfl_down(p, off);
        if (t == 0) out[0] = -p / (float)BSZ;
    }
}

// ---------------------------------------------------------------------------
extern "C" void kernel_launch(void* const* d_in, const int* in_sizes, int n_in,
                              void* d_out, int out_size, void* d_ws, size_t ws_size,
                              hipStream_t stream)
{
    (void)in_sizes; (void)n_in; (void)out_size; (void)ws_size;
    const float* text = (const float*)d_in[0];   // [64,128,768] fp32
    const float* img  = (const float*)d_in[1];   // [64, 64,768] fp32
    const int*   tm   = (const int*)d_in[2];     // [64,128] int32
    const int*   im   = (const int*)d_in[3];     // [64, 64] int32
    float* out = (float*)d_out;                  // [1 + 64*128*768] fp32

    // workspace layout (bytes); total ~21 MB
    char* ws = (char*)d_ws;
    unsigned short* A = (unsigned short*)(ws);                   // 12.58 MB fp16
    unsigned short* B = (unsigned short*)(ws + 12582912);        //  6.29 MB fp16
    float* S = (float*)(ws + 18874368);                          // 16 KB
    float* W = (float*)(ws + 18890752);                          //  2 MB

    k_prep<<<(TQ + IQ) / 256, 256, 0, stream>>>(
        (const float4*)text, (const float4*)img, (ushort4*)A, (ushort4*)B);

    k_scores<<<512, 512, 0, stream>>>(A, B, tm, im, S, W);

    dim3 g2(BSZ, 3, 8);
    k_i2s<<<g2, 256, 0, stream>>>(W, img, S, out);
}

// Round 10
// 264.666 us; speedup vs baseline: 1.2905x; 1.2905x over previous
//
#include <hip/hip_runtime.h>
#include <math.h>

// Problem constants (B, N, L, D) from the reference setup_inputs().
#define BSZ 64
#define NN  128
#define LL  64
#define DD  768
#define NEGV (-9e9f)

#define TQ (BSZ * NN * DD / 4)   // text float4 count  = 1572864
#define IQ (BSZ * LL * DD / 4)   // image float4 count =  786432

typedef _Float16 f16x8 __attribute__((ext_vector_type(8)));   // 8 f16 = 4 VGPRs
typedef __attribute__((ext_vector_type(16))) float f32x16;    // MFMA 32x32 accum

// async 16B global -> LDS (dest = wave-uniform base + lane*16)
__device__ __forceinline__ void gl_lds16(const void* g, void* l) {
    __builtin_amdgcn_global_load_lds(
        (const __attribute__((address_space(1))) void*)g,
        (__attribute__((address_space(3))) void*)l, 16, 0, 0);
}

// ---------------------------------------------------------------------------
// Kernel 0: fp32 -> fp16 (RTN). Error 2^-11 relative; N(0,1) inputs.
// ---------------------------------------------------------------------------
__global__ __launch_bounds__(256) void k_prep(
    const float4* __restrict__ t4, const float4* __restrict__ g4,
    ushort4* __restrict__ A, ushort4* __restrict__ B)
{
    int id = blockIdx.x * 256 + threadIdx.x;
    const float4* src; ushort4* dst; int idx;
    if (id < TQ) { src = t4; dst = A; idx = id; }
    else         { src = g4; dst = B; idx = id - TQ; }
    float4 x = src[idx];
    _Float16 h0 = (_Float16)x.x, h1 = (_Float16)x.y;
    _Float16 h2 = (_Float16)x.z, h3 = (_Float16)x.w;
    ushort4 o;
    o.x = __builtin_bit_cast(unsigned short, h0);
    o.y = __builtin_bit_cast(unsigned short, h1);
    o.z = __builtin_bit_cast(unsigned short, h2);
    o.w = __builtin_bit_cast(unsigned short, h3);
    dst[idx] = o;
}

// ---------------------------------------------------------------------------
// Stage one BK=64 chunk (A 16 KB + B 16 KB) into LDS, k8-major layout
// (zero-conflict, R9-measured):  slot = k8*128 + r  (k8 in [0,8), r in [0,128)).
// global_load_lds dest = wave-uniform base + lane*16; global src is per-lane,
// so src = r*DD + k0 + k8*8 realizes the k8-major layout with linear dest.
// 256 threads x 4 calls x (A,B) = 2048 x 16B slots = 32 KB.
// ---------------------------------------------------------------------------
__device__ __forceinline__ void stage_chunk(
    const unsigned short* __restrict__ pa, const unsigned short* __restrict__ pb,
    int k0, char* buf, int wave, int lane)
{
#pragma unroll
    for (int cc = 0; cc < 4; ++cc) {
        int s  = cc * 256 + wave * 64 + lane;   // 0..1023
        int k8 = s >> 7, r = s & 127;
        gl_lds16(pa + (size_t)r * DD + k0 + k8 * 8, buf + cc * 4096 + wave * 1024);
        gl_lds16(pb + (size_t)r * DD + k0 + k8 * 8, buf + 16384 + cc * 4096 + wave * 1024);
    }
}

// ---------------------------------------------------------------------------
// Kernel 1 (R10): R9's VERIFIED 32x32x16-MFMA + in-register epilogue math,
// shrunk to the proven no-spill shape (R1/R8: 256 thr, 64-reg accumulator).
// Block = 128x128 tile = 1 text i x 2 image j (grid 2048, R1 swizzle).
// 4 waves = 2 row-halves (wm) x 2 j's (wn); wave tile 64x64 = f32x16[2][2].
// R9 spill lesson: in-register epilogue keeps acc live as ARCH VGPRs (shfl);
// >~100 live arch regs spills (R3/R6/R9). 64 live here -> fits 88-reg budget.
// Epilogue: row softmax fully in-wave (rows local); col softmax via 3x2x128
// LDS partial-merge (exact max-merge); S cross-wave via srowL; diag W from
// registers + row stats. No Cs round-trip (deletes R8's 66KB tile + scans).
// ---------------------------------------------------------------------------
__global__ __launch_bounds__(256, 2) void k_scores(
    const unsigned short* __restrict__ A, const unsigned short* __restrict__ B,
    const int* __restrict__ tmask, const int* __restrict__ imask,
    float* __restrict__ S, float* __restrict__ W)
{
    __shared__ __align__(16) char smem[65536];   // [2][A 16KB | B 16KB]
    __shared__ float tmi[NN], imj[NN];
    __shared__ float rowmL[NN], rowsL[NN];       // diag row stats
    __shared__ float cpm[2][NN], cps[2][NN], cpw[2][NN];  // col partials by wm
    __shared__ float srowL[4];
    __shared__ float colred[NN];

    // 4x4 block-group swizzle for L2 locality (R1-proven)
    const int bid = blockIdx.x;            // 0..2047
    const int grp = bid >> 4, idx = bid & 15;
    const int i  = (grp >> 3) * 4 + (idx >> 2);   // 0..63
    const int jj = (grp & 7) * 4 + (idx & 3);     // 0..31
    const int j0 = jj * 2;

    const int tid  = threadIdx.x;
    const int wave = tid >> 6;     // 0..3
    const int lane = tid & 63;
    const int l31  = lane & 31;
    const int hi   = lane >> 5;
    const int wm   = wave >> 1;    // row half: rows wm*64..+64
    const int wn   = wave & 1;     // j half:  cols wn*64..+64 (j = j0+wn)

    const unsigned short* pa = A + (size_t)i * NN * DD;
    const unsigned short* pb = B + (size_t)j0 * LL * DD;

    const f32x16 zf16 = {0.f,0.f,0.f,0.f,0.f,0.f,0.f,0.f,
                         0.f,0.f,0.f,0.f,0.f,0.f,0.f,0.f};
    f32x16 acc[2][2];
    acc[0][0] = zf16; acc[0][1] = zf16; acc[1][0] = zf16; acc[1][1] = zf16;

    stage_chunk(pa, pb, 0, smem, wave, lane);
    __syncthreads();

    for (int c = 0; c < 12; ++c) {
        char* cur = smem + (c & 1) * 32768;
        if (c + 1 < 12)
            stage_chunk(pa, pb, (c + 1) << 6, smem + ((c + 1) & 1) * 32768, wave, lane);
#pragma unroll
        for (int s16 = 0; s16 < 4; ++s16) {
            const int k8 = s16 * 2 + hi;
            f16x8 a0 = *(const f16x8*)(cur + ((k8 << 7) + wm * 64 + l31) * 16);
            f16x8 a1 = *(const f16x8*)(cur + ((k8 << 7) + wm * 64 + 32 + l31) * 16);
            f16x8 b0 = *(const f16x8*)(cur + 16384 + ((k8 << 7) + wn * 64 + l31) * 16);
            f16x8 b1 = *(const f16x8*)(cur + 16384 + ((k8 << 7) + wn * 64 + 32 + l31) * 16);
            acc[0][0] = __builtin_amdgcn_mfma_f32_32x32x16_f16(a0, b0, acc[0][0], 0, 0, 0);
            acc[0][1] = __builtin_amdgcn_mfma_f32_32x32x16_f16(a0, b1, acc[0][1], 0, 0, 0);
            acc[1][0] = __builtin_amdgcn_mfma_f32_32x32x16_f16(a1, b0, acc[1][0], 0, 0, 0);
            acc[1][1] = __builtin_amdgcn_mfma_f32_32x32x16_f16(a1, b1, acc[1][1], 0, 0, 0);
        }
        __syncthreads();
    }

    // ---- masks ----
    if (tid < NN) tmi[tid] = tmask[i * NN + tid] ? 1.f : 0.f;
    else          imj[tid - NN] = imask[j0 * LL + (tid - NN)] ? 1.f : 0.f;
    __syncthreads();

    const float imv0 = imj[wn * 64 + l31];        // col mask, nt=0
    const float imv1 = imj[wn * 64 + 32 + l31];   // col mask, nt=1

    // ---- mask acc in place (R9-verified): C/D col=l31(+nt*32),
    //      row_local = (q&3) + 8*(q>>2) + 4*hi (+mt*32, +wm*64) ----
#pragma unroll
    for (int mt = 0; mt < 2; ++mt)
#pragma unroll
        for (int q = 0; q < 16; ++q) {
            int rl = (q & 3) + 8 * (q >> 2) + 4 * hi;
            float tmv = tmi[wm * 64 + mt * 32 + rl];
            float v0 = acc[mt][0][q], v1 = acc[mt][1][q];
            acc[mt][0][q] = (tmv != 0.f && imv0 != 0.f && v0 != 0.f) ? v0 : NEGV;
            acc[mt][1][q] = (tmv != 0.f && imv1 != 0.f && v1 != 0.f) ? v1 : NEGV;
        }

    const bool diag = (jj == (i >> 1));
    const int  jhd  = i & 1;

    // ---- row softmax (wave's 64 rows x its full 64 cols), in-register ----
    float srow = 0.f;
#pragma unroll
    for (int mt = 0; mt < 2; ++mt)
#pragma unroll
        for (int q = 0; q < 16; ++q) {
            float v0 = acc[mt][0][q], v1 = acc[mt][1][q];
            float m = fmaxf(v0, v1);
#pragma unroll
            for (int d = 1; d <= 16; d <<= 1) m = fmaxf(m, __shfl_xor(m, d));
            float e0 = __expf(v0 - m), e1 = __expf(v1 - m);
            float ss = e0 + e1;
            float ws = imv0 * e0 * v0 + imv1 * e1 * v1;
#pragma unroll
            for (int d = 1; d <= 16; d <<= 1) {
                ss += __shfl_xor(ss, d);
                ws += __shfl_xor(ws, d);
            }
            int rl = (q & 3) + 8 * (q >> 2) + 4 * hi;
            srow += tmi[wm * 64 + mt * 32 + rl] * (ws / ss);
            if (diag && wn == jhd && l31 == 0) {      // stash row stats for W
                rowmL[wm * 64 + mt * 32 + rl] = m;
                rowsL[wm * 64 + mt * 32 + rl] = ss;
            }
        }
    srow += __shfl_xor(srow, 32);             // the two hi-halves hold different rows
    if (lane == 0) srowL[wave] = srow;

    // ---- col softmax partials (wave's 64 cols over its 64 rows) ----
#pragma unroll
    for (int nt = 0; nt < 2; ++nt) {
        float m = -INFINITY;
#pragma unroll
        for (int mt = 0; mt < 2; ++mt)
#pragma unroll
            for (int q = 0; q < 16; ++q) m = fmaxf(m, acc[mt][nt][q]);
        m = fmaxf(m, __shfl_xor(m, 32));
        float ss = 0.f, ws = 0.f;
#pragma unroll
        for (int mt = 0; mt < 2; ++mt)
#pragma unroll
            for (int q = 0; q < 16; ++q) {
                int rl = (q & 3) + 8 * (q >> 2) + 4 * hi;
                float tmv = tmi[wm * 64 + mt * 32 + rl];
                float v = acc[mt][nt][q];
                float e = __expf(v - m);
                ss += e;
                ws += tmv * e * v;
            }
        ss += __shfl_xor(ss, 32);
        ws += __shfl_xor(ws, 32);
        if (hi == 0) {
            int cg = wn * 64 + nt * 32 + l31;
            cpm[wm][cg] = m; cps[wm][cg] = ss; cpw[wm][cg] = ws;
        }
    }
    __syncthreads();

    // ---- merge col partials across the two row-halves (exact max-merge) ----
    if (tid < NN) {
        float m0 = cpm[0][tid], m1 = cpm[1][tid];
        float m = fmaxf(m0, m1);
        float f0 = __expf(m0 - m), f1 = __expf(m1 - m);
        float ss = cps[0][tid] * f0 + cps[1][tid] * f1;
        float ws = cpw[0][tid] * f0 + cpw[1][tid] * f1;
        colred[tid] = imj[tid] * (ws / ss);
    }
    __syncthreads();

    // ---- S[i][j0+jh] = (srow(wm0) + srow(wm1) + sum_l colred) / N ----
    if (tid < NN) {
        int jh = tid >> 6, t = tid & 63;
        float p = colred[jh * 64 + t];
#pragma unroll
        for (int off = 32; off; off >>= 1) p += __shfl_down(p, off);
        if (t == 0)
            S[i * BSZ + j0 + jh] = (srowL[jh] + srowL[2 + jh] + p) / (float)NN;
    }

    // ---- diagonal W (32 blocks): W[i][l][n] = exp(vm - m_row)/ss_row ----
    if (diag && wn == jhd) {
        float* Wb = W + (size_t)i * LL * NN;
#pragma unroll
        for (int nt = 0; nt < 2; ++nt) {
            int l = nt * 32 + l31;
#pragma unroll
            for (int mt = 0; mt < 2; ++mt)
#pragma unroll
                for (int qq = 0; qq < 4; ++qq) {
                    int n0 = wm * 64 + mt * 32 + 8 * qq + 4 * hi;
                    float4 w;
                    w.x = __expf(acc[mt][nt][qq * 4 + 0] - rowmL[n0 + 0]) / rowsL[n0 + 0];
                    w.y = __expf(acc[mt][nt][qq * 4 + 1] - rowmL[n0 + 1]) / rowsL[n0 + 1];
                    w.z = __expf(acc[mt][nt][qq * 4 + 2] - rowmL[n0 + 2]) / rowsL[n0 + 2];
                    w.w = __expf(acc[mt][nt][qq * 4 + 3] - rowmL[n0 + 3]) / rowsL[n0 + 3];
                    *(float4*)(Wb + (size_t)l * NN + n0) = w;
                }
        }
    }
}

// ---------------------------------------------------------------------------
// Kernel 2: text_emb_i2s[b,n,d] = sum_l W[b][l][n] * img[b][l][d]
// Grid: (64 b, 3 d-chunks of 256, 8 n-groups of 16).  W chunk staged in LDS.
// k_loss fused into the tail of block (0,0,0).
// ---------------------------------------------------------------------------
__global__ __launch_bounds__(256) void k_i2s(
    const float* __restrict__ W, const float* __restrict__ img,
    const float* __restrict__ S, float* __restrict__ out)
{
    __shared__ float Ws[LL][16];   // 4 KB
    const int b  = blockIdx.x;
    const int ng = blockIdx.z * 16;
    const int d  = blockIdx.y * 256 + threadIdx.x;
    const float* Wb = W + (size_t)b * LL * NN;

    {   // stage W[l][ng..ng+15]: 1024 floats, 4 per thread
        int t4 = threadIdx.x * 4;
        int l = t4 >> 4, noff = t4 & 15;
        float4 w = *(const float4*)(Wb + (size_t)l * NN + ng + noff);
        Ws[l][noff + 0] = w.x; Ws[l][noff + 1] = w.y;
        Ws[l][noff + 2] = w.z; Ws[l][noff + 3] = w.w;
    }
    __syncthreads();

    const float* ib = img + (size_t)b * LL * DD;
    float* ob = out + 1 + (size_t)b * NN * DD + (size_t)ng * DD;  // slot 0 = loss

    float acc[16];
#pragma unroll
    for (int q = 0; q < 16; q++) acc[q] = 0.f;
    for (int l = 0; l < LL; l++) {
        float g = ib[(size_t)l * DD + d];
#pragma unroll
        for (int q = 0; q < 16; q++)
            acc[q] = fmaf(Ws[l][q], g, acc[q]);   // Ws read is broadcast
    }
#pragma unroll
    for (int q = 0; q < 16; q++)
        ob[(size_t)q * DD + d] = acc[q];

    // fused loss: loss = -sum_i( 2*S[i,i] - lse_row_i(S) - lse_col_i(S) ) / B
    if (blockIdx.x == 0 && blockIdx.y == 0 && blockIdx.z == 0 && threadIdx.x < 64) {
        const int t = threadIdx.x;  // 0..63
        float diag = S[t * BSZ + t];
        float m1 = -INFINITY, m2 = -INFINITY;
        for (int jj = 0; jj < BSZ; jj++) {
            m1 = fmaxf(m1, S[t * BSZ + jj]);
            m2 = fmaxf(m2, S[jj * BSZ + t]);
        }
        float s1 = 0.f, s2 = 0.f;
        for (int jj = 0; jj < BSZ; jj++) {
            s1 += __expf(S[t * BSZ + jj] - m1);
            s2 += __expf(S[jj * BSZ + t] - m2);
        }
        float p = 2.f * diag - (m1 + logf(s1)) - (m2 + logf(s2));
#pragma unroll
        for (int off = 32; off; off >>= 1) p += __shfl_down(p, off);
        if (t == 0) out[0] = -p / (float)BSZ;
    }
}

// ---------------------------------------------------------------------------
extern "C" void kernel_launch(void* const* d_in, const int* in_sizes, int n_in,
                              void* d_out, int out_size, void* d_ws, size_t ws_size,
                              hipStream_t stream)
{
    (void)in_sizes; (void)n_in; (void)out_size; (void)ws_size;
    const float* text = (const float*)d_in[0];   // [64,128,768] fp32
    const float* img  = (const float*)d_in[1];   // [64, 64,768] fp32
    const int*   tm   = (const int*)d_in[2];     // [64,128] int32
    const int*   im   = (const int*)d_in[3];     // [64, 64] int32
    float* out = (float*)d_out;                  // [1 + 64*128*768] fp32

    // workspace layout (bytes); total ~21 MB
    char* ws = (char*)d_ws;
    unsigned short* A = (unsigned short*)(ws);                   // 12.58 MB fp16
    unsigned short* B = (unsigned short*)(ws + 12582912);        //  6.29 MB fp16
    float* S = (float*)(ws + 18874368);                          // 16 KB
    float* W = (float*)(ws + 18890752);                          //  2 MB

    k_prep<<<(TQ + IQ) / 256, 256, 0, stream>>>(
        (const float4*)text, (const float4*)img, (ushort4*)A, (ushort4*)B);

    k_scores<<<BSZ * (BSZ / 2), 256, 0, stream>>>(A, B, tm, im, S, W);

    dim3 g2(BSZ, 3, 8);
    k_i2s<<<g2, 256, 0, stream>>>(W, img, S, out);
}

// Round 11
// 197.972 us; speedup vs baseline: 1.7252x; 1.3369x over previous
//
#include <hip/hip_runtime.h>
#include <math.h>

// Problem constants (B, N, L, D) from the reference setup_inputs().
#define BSZ 64
#define NN  128
#define LL  64
#define DD  768
#define NEGV (-9e9f)

#define TQ (BSZ * NN * DD / 4)   // text float4 count  = 1572864
#define IQ (BSZ * LL * DD / 4)   // image float4 count =  786432

typedef _Float16 f16x8 __attribute__((ext_vector_type(8)));  // 8 f16 = 4 VGPRs
typedef __attribute__((ext_vector_type(4))) float f32x4;     // MFMA 16x16 accum

// async 16B global -> LDS (dest = wave-uniform base + lane*16)
__device__ __forceinline__ void gl_lds16(const void* g, void* l) {
    __builtin_amdgcn_global_load_lds(
        (const __attribute__((address_space(1))) void*)g,
        (__attribute__((address_space(3))) void*)l, 16, 0, 0);
}

// ---------------------------------------------------------------------------
// Kernel 0: fp32 -> fp16 (RTN). Error 2^-11 relative; N(0,1) inputs.
// ---------------------------------------------------------------------------
__global__ __launch_bounds__(256) void k_prep(
    const float4* __restrict__ t4, const float4* __restrict__ g4,
    ushort4* __restrict__ A, ushort4* __restrict__ B)
{
    int id = blockIdx.x * 256 + threadIdx.x;
    const float4* src; ushort4* dst; int idx;
    if (id < TQ) { src = t4; dst = A; idx = id; }
    else         { src = g4; dst = B; idx = id - TQ; }
    float4 x = src[idx];
    _Float16 h0 = (_Float16)x.x, h1 = (_Float16)x.y;
    _Float16 h2 = (_Float16)x.z, h3 = (_Float16)x.w;
    ushort4 o;
    o.x = __builtin_bit_cast(unsigned short, h0);
    o.y = __builtin_bit_cast(unsigned short, h1);
    o.z = __builtin_bit_cast(unsigned short, h2);
    o.w = __builtin_bit_cast(unsigned short, h3);
    dst[idx] = o;
}

// ---------------------------------------------------------------------------
// Stage one 32 KB chunk (A: 128 rows x 64 k f16, B: 128 rows x 64 k) into LDS.
// LDS slot for (r, k8): r*8 + (k8 ^ (r&7)), 16B per slot (XOR bank swizzle).
// global_load_lds dest = wave-uniform base + lane*16; slot index is linear
// in (call, wave, lane): slot = c*256 + wave*64 + lane.
// [Session ledger: this BK=64/12-chunk structure = 87.5 us verified (R2/R8).
//  BK=32 (R7): 160 us. 512-thr tiles (R3/R6/R9): VGPR spill. In-register
//  shfl epilogue (R10): 180 us (serial cross-lane chains). KEEP AS IS.]
// ---------------------------------------------------------------------------
__device__ __forceinline__ void stage_chunk(
    const unsigned short* __restrict__ pa, const unsigned short* __restrict__ pb,
    int k0, char* buf, int wave, int lane)
{
    int rsub = lane >> 3;     // 0..7
    int k8s  = lane & 7;
#pragma unroll
    for (int c = 0; c < 4; c++) {
        int r  = c * 32 + wave * 8 + rsub;
        int k8 = k8s ^ (r & 7);
        gl_lds16(pa + (size_t)r * DD + k0 + k8 * 8, buf + c * 4096 + wave * 1024);
        gl_lds16(pb + (size_t)r * DD + k0 + k8 * 8, buf + 16384 + c * 4096 + wave * 1024);
    }
}

// ---------------------------------------------------------------------------
// Kernel 1: one block per (i, jj) where jj covers j = {2jj, 2jj+1}.
// C[128][128] = text[i] @ [image[j0]; image[j1]]^T, single-pass fp16 MFMA,
// LDS-staged via global_load_lds, double-buffered, 12 chunks of BK=64.
// Measured (R2/R8): 87.5 us, MfmaUtil 24%, occ 20%, VGPR 88, FETCH 31 MB.
// ---------------------------------------------------------------------------
__global__ __launch_bounds__(256, 2) void k_scores(
    const unsigned short* __restrict__ A, const unsigned short* __restrict__ B,
    const int* __restrict__ tmask, const int* __restrict__ imask,
    float* __restrict__ S, float* __restrict__ W)
{
    union SmemU {
        char  stage[2][32768];     // [buf][A 16KB | B 16KB]
        float Cs[NN][129];         // 66 KB epilogue tile (stride 129: 2-way free)
    };
    __shared__ SmemU u;
    __shared__ float tmi[NN];
    __shared__ float imj[NN];      // 128 cols = two j's
    __shared__ float rowred[256];
    __shared__ float colred[NN];
    __shared__ float rowm[256], rowsm[256];          // phase-1 row stats stash
    __shared__ float colm[256], colp1[256], colp2[256];  // phase-2 partials

    // 4x4 block-group swizzle for L2 locality (~1.6 MB working set / group)
    const int bid = blockIdx.x;
    const int grp = bid >> 4, idx = bid & 15;
    const int i  = (grp >> 3) * 4 + (idx >> 2);   // 0..63
    const int jj = (grp & 7) * 4 + (idx & 3);     // 0..31
    const int j0 = jj * 2;

    const int tid  = threadIdx.x;
    const int wave = tid >> 6;
    const int lane = tid & 63;
    const int quad = lane >> 4;
    const int l15  = lane & 15;
    const int rh   = wave & 1;     // row half (64 rows)
    const int ch   = wave >> 1;    // col half (64 cols)

    if (tid < NN) {
        tmi[tid] = tmask[i * NN + tid] ? 1.f : 0.f;
        imj[tid] = imask[j0 * LL + tid] ? 1.f : 0.f;   // two j's contiguous
    }

    const unsigned short* pa = A + (size_t)i * NN * DD;
    const unsigned short* pb = B + (size_t)j0 * LL * DD;

    f32x4 acc[4][4];
    const f32x4 zf = {0.f, 0.f, 0.f, 0.f};
#pragma unroll
    for (int tr = 0; tr < 4; tr++)
#pragma unroll
        for (int tc = 0; tc < 4; tc++) acc[tr][tc] = zf;

    stage_chunk(pa, pb, 0, u.stage[0], wave, lane);
    __syncthreads();

    for (int c = 0; c < 12; c++) {
        if (c + 1 < 12)
            stage_chunk(pa, pb, (c + 1) << 6, u.stage[(c + 1) & 1], wave, lane);
        const char* Ab = u.stage[c & 1];
        const char* Bb = Ab + 16384;
#pragma unroll
        for (int s = 0; s < 2; s++) {
            int k8q = s * 4 + quad;
            int sw  = k8q ^ (l15 & 7);
            f16x8 af[4], bfr[4];
#pragma unroll
            for (int t = 0; t < 4; t++) {
                int row = rh * 64 + t * 16 + l15;
                af[t]  = *(const f16x8*)(Ab + ((row << 3) + sw) * 16);
                int col = ch * 64 + t * 16 + l15;
                bfr[t] = *(const f16x8*)(Bb + ((col << 3) + sw) * 16);
            }
#pragma unroll
            for (int tr = 0; tr < 4; tr++)
#pragma unroll
                for (int tc = 0; tc < 4; tc++)
                    acc[tr][tc] = __builtin_amdgcn_mfma_f32_16x16x32_f16(
                        af[tr], bfr[tc], acc[tr][tc], 0, 0, 0);
        }
        __syncthreads();
    }

    // masked att -> Cs.  att = (mask && dot != 0) ? dot : NEG
    // C/D layout per 16x16 tile: row = quad*4 + rr, col = l15
#pragma unroll
    for (int tr = 0; tr < 4; tr++) {
        int rb = rh * 64 + tr * 16 + quad * 4;
#pragma unroll
        for (int tc = 0; tc < 4; tc++) {
            int col = ch * 64 + tc * 16 + l15;
            float im = imj[col];
#pragma unroll
            for (int rr = 0; rr < 4; rr++) {
                int row = rb + rr;
                float v = acc[tr][tc][rr];
                bool keep = (tmi[row] != 0.f) && (im != 0.f) && (v != 0.f);
                u.Cs[row][col] = keep ? v : NEGV;
            }
        }
    }
    __syncthreads();

    // phase 1: row softmax over l for each (jh, n) -- all 256 threads
    {
        int jh = tid >> 7, n = tid & 127;
        const float* Crow = &u.Cs[n][jh * 64];
        float m = -INFINITY;
        for (int l = 0; l < LL; l++) m = fmaxf(m, Crow[l]);
        float ssum = 0.f, ws = 0.f;
        for (int l = 0; l < LL; l++) {
            float v = Crow[l];
            float e = __expf(v - m);      // all-NEG row -> uniform
            ssum += e;
            ws += imj[jh * 64 + l] * e * v;
        }
        rowm[tid] = m;                    // stash for diagonal W (bit-exact)
        rowsm[tid] = ssum;
        rowred[tid] = tmi[n] * (ws / ssum);
    }
    __syncthreads();

    // phase 2: col softmax, ALL 256 threads, 2 per column (split over n-halves)
    {
        int c  = tid & 127;              // column 0..127
        int n0 = (tid >> 7) * 64;        // row half start
        float m = -INFINITY;
        for (int n = n0; n < n0 + 64; n++) m = fmaxf(m, u.Cs[n][c]);
        colm[tid] = m;
        __syncthreads();
        m = fmaxf(colm[tid], colm[tid ^ 128]);
        float ssum = 0.f, ws = 0.f;
        for (int n = n0; n < n0 + 64; n++) {
            float v = u.Cs[n][c];
            float e = __expf(v - m);
            ssum += e;
            ws += tmi[n] * e * v;
        }
        colp1[tid] = ssum;
        colp2[tid] = ws;
    }
    __syncthreads();
    if (tid < NN) {
        float ssum = colp1[tid] + colp1[tid + 128];
        float ws   = colp2[tid] + colp2[tid + 128];
        colred[tid] = imj[tid] * (ws / ssum);
    }

    // diagonal W (32/2048 blocks): write pass only, reusing phase-1 stats.
    if (jj == (i >> 1) && tid < NN) {
        int jh = i & 1;
        int n = tid;
        float m   = rowm[jh * 128 + n];
        float inv = 1.f / rowsm[jh * 128 + n];
        const float* Crow = &u.Cs[n][jh * 64];
        float* Wb = W + (size_t)i * LL * NN;
        for (int l = 0; l < LL; l++)
            Wb[(size_t)l * NN + n] = __expf(Crow[l] - m) * inv;  // coalesced over n
    }
    __syncthreads();

    // S[i][j0+jh] = (sum_n rowred + sum_l colred) / N   (waves 0,1)
    if (tid < NN) {
        int jh = tid >> 6, t = tid & 63;
        float p = rowred[jh * 128 + t] + rowred[jh * 128 + 64 + t] + colred[jh * 64 + t];
#pragma unroll
        for (int off = 32; off; off >>= 1) p += __shfl_down(p, off);
        if (t == 0) S[i * BSZ + j0 + jh] = p / (float)NN;
    }
}

// ---------------------------------------------------------------------------
// Kernel 2 (R11): text_emb_i2s[b,n,d] = sum_l W[b][l][n] * img[b][l][d]
// Grid: (64 b, 3 d-chunks of 256, 2 n-groups of 64) -- was 8 groups of 16.
// img d-chunk re-read drops 8x -> 2x (~98 MB -> ~53 MB total traffic).
// Per-(n,d) fmaf chain identical order to R8 -> bit-identical output.
// 64 accumulators/thread, all compile-time indexed (no scratch risk).
// k_loss fused into the tail of block (0,0,0).
// ---------------------------------------------------------------------------
__global__ __launch_bounds__(256) void k_i2s(
    const float* __restrict__ W, const float* __restrict__ img,
    const float* __restrict__ S, float* __restrict__ out)
{
    __shared__ float Ws[LL][64];   // 16 KB: W[l][ng..ng+63]
    const int b  = blockIdx.x;
    const int ng = blockIdx.z * 64;
    const int d  = blockIdx.y * 256 + threadIdx.x;
    const float* Wb = W + (size_t)b * LL * NN;

    {   // stage W[l][ng..ng+63]: 4096 floats, 4 float4 per thread
#pragma unroll
        for (int rep = 0; rep < 4; rep++) {
            int fidx = (rep * 256 + threadIdx.x) * 4;   // 0..4092
            int l = fidx >> 6, noff = fidx & 63;
            float4 w = *(const float4*)(Wb + (size_t)l * NN + ng + noff);
            *(float4*)(&Ws[l][noff]) = w;
        }
    }
    __syncthreads();

    const float* ib = img + (size_t)b * LL * DD;
    float* ob = out + 1 + (size_t)b * NN * DD + (size_t)ng * DD;  // slot 0 = loss

    float acc[64];
#pragma unroll
    for (int q = 0; q < 64; q++) acc[q] = 0.f;
    for (int l = 0; l < LL; l++) {
        float g = ib[(size_t)l * DD + d];
#pragma unroll
        for (int q = 0; q < 64; q++)
            acc[q] = fmaf(Ws[l][q], g, acc[q]);   // Ws read is broadcast
    }
#pragma unroll
    for (int q = 0; q < 64; q++)
        ob[(size_t)q * DD + d] = acc[q];

    // fused loss: loss = -sum_i( 2*S[i,i] - lse_row_i(S) - lse_col_i(S) ) / B
    if (blockIdx.x == 0 && blockIdx.y == 0 && blockIdx.z == 0 && threadIdx.x < 64) {
        const int t = threadIdx.x;  // 0..63
        float diag = S[t * BSZ + t];
        float m1 = -INFINITY, m2 = -INFINITY;
        for (int jj = 0; jj < BSZ; jj++) {
            m1 = fmaxf(m1, S[t * BSZ + jj]);
            m2 = fmaxf(m2, S[jj * BSZ + t]);
        }
        float s1 = 0.f, s2 = 0.f;
        for (int jj = 0; jj < BSZ; jj++) {
            s1 += __expf(S[t * BSZ + jj] - m1);
            s2 += __expf(S[jj * BSZ + t] - m2);
        }
        float p = 2.f * diag - (m1 + logf(s1)) - (m2 + logf(s2));
#pragma unroll
        for (int off = 32; off; off >>= 1) p += __shfl_down(p, off);
        if (t == 0) out[0] = -p / (float)BSZ;
    }
}

// ---------------------------------------------------------------------------
extern "C" void kernel_launch(void* const* d_in, const int* in_sizes, int n_in,
                              void* d_out, int out_size, void* d_ws, size_t ws_size,
                              hipStream_t stream)
{
    (void)in_sizes; (void)n_in; (void)out_size; (void)ws_size;
    const float* text = (const float*)d_in[0];   // [64,128,768] fp32
    const float* img  = (const float*)d_in[1];   // [64, 64,768] fp32
    const int*   tm   = (const int*)d_in[2];     // [64,128] int32
    const int*   im   = (const int*)d_in[3];     // [64, 64] int32
    float* out = (float*)d_out;                  // [1 + 64*128*768] fp32

    // workspace layout (bytes); total ~21 MB
    char* ws = (char*)d_ws;
    unsigned short* A = (unsigned short*)(ws);                   // 12.58 MB fp16
    unsigned short* B = (unsigned short*)(ws + 12582912);        //  6.29 MB fp16
    float* S = (float*)(ws + 18874368);                          // 16 KB
    float* W = (float*)(ws + 18890752);                          //  2 MB

    k_prep<<<(TQ + IQ) / 256, 256, 0, stream>>>(
        (const float4*)text, (const float4*)img, (ushort4*)A, (ushort4*)B);

    k_scores<<<BSZ * (BSZ / 2), 256, 0, stream>>>(A, B, tm, im, S, W);

    dim3 g2(BSZ, 3, 2);
    k_i2s<<<g2, 256, 0, stream>>>(W, img, S, out);
}

// Round 12
// 182.349 us; speedup vs baseline: 1.8730x; 1.0857x over previous
//
#include <hip/hip_runtime.h>
#include <math.h>

// Problem constants (B, N, L, D) from the reference setup_inputs().
#define BSZ 64
#define NN  128
#define LL  64
#define DD  768
#define NEGV (-9e9f)

#define TQ (BSZ * NN * DD / 4)   // text float4 count  = 1572864
#define IQ (BSZ * LL * DD / 4)   // image float4 count =  786432

typedef _Float16 f16x8 __attribute__((ext_vector_type(8)));  // 8 f16 = 4 VGPRs
typedef __attribute__((ext_vector_type(4))) float f32x4;     // MFMA 16x16 accum

// async 16B global -> LDS (dest = wave-uniform base + lane*16)
__device__ __forceinline__ void gl_lds16(const void* g, void* l) {
    __builtin_amdgcn_global_load_lds(
        (const __attribute__((address_space(1))) void*)g,
        (__attribute__((address_space(3))) void*)l, 16, 0, 0);
}

// ---------------------------------------------------------------------------
// Kernel 0: fp32 -> fp16 (RTN). Error 2^-11 relative; N(0,1) inputs.
// ---------------------------------------------------------------------------
__global__ __launch_bounds__(256) void k_prep(
    const float4* __restrict__ t4, const float4* __restrict__ g4,
    ushort4* __restrict__ A, ushort4* __restrict__ B)
{
    int id = blockIdx.x * 256 + threadIdx.x;
    const float4* src; ushort4* dst; int idx;
    if (id < TQ) { src = t4; dst = A; idx = id; }
    else         { src = g4; dst = B; idx = id - TQ; }
    float4 x = src[idx];
    _Float16 h0 = (_Float16)x.x, h1 = (_Float16)x.y;
    _Float16 h2 = (_Float16)x.z, h3 = (_Float16)x.w;
    ushort4 o;
    o.x = __builtin_bit_cast(unsigned short, h0);
    o.y = __builtin_bit_cast(unsigned short, h1);
    o.z = __builtin_bit_cast(unsigned short, h2);
    o.w = __builtin_bit_cast(unsigned short, h3);
    dst[idx] = o;
}

// ---------------------------------------------------------------------------
// Stage one 32 KB chunk (A: 128 rows x 64 k f16, B: 128 rows x 64 k) into LDS.
// LDS slot for (r, k8): r*8 + (k8 ^ (r&7)), 16B per slot (XOR bank swizzle).
// [Session ledger: this BK=64/12-chunk structure = 87.5 us verified (fast
//  container; 113 us on slow container, same profile). BK=32: 160. 512-thr:
//  spill. In-register shfl epilogue: 180. KEEP AS IS.]
// ---------------------------------------------------------------------------
__device__ __forceinline__ void stage_chunk(
    const unsigned short* __restrict__ pa, const unsigned short* __restrict__ pb,
    int k0, char* buf, int wave, int lane)
{
    int rsub = lane >> 3;     // 0..7
    int k8s  = lane & 7;
#pragma unroll
    for (int c = 0; c < 4; c++) {
        int r  = c * 32 + wave * 8 + rsub;
        int k8 = k8s ^ (r & 7);
        gl_lds16(pa + (size_t)r * DD + k0 + k8 * 8, buf + c * 4096 + wave * 1024);
        gl_lds16(pb + (size_t)r * DD + k0 + k8 * 8, buf + 16384 + c * 4096 + wave * 1024);
    }
}

// ---------------------------------------------------------------------------
// Kernel 1: one block per (i, jj) where jj covers j = {2jj, 2jj+1}.
// C[128][128] = text[i] @ [image[j0]; image[j1]]^T, single-pass fp16 MFMA,
// LDS-staged via global_load_lds, double-buffered, 12 chunks of BK=64.
// R12 delta: diagonal pass writes Wh = P^T fp16 [i][n][l] (k-contiguous
// A-operand for the MFMA k_i2s) instead of fp32 W. Otherwise frozen.
// ---------------------------------------------------------------------------
__global__ __launch_bounds__(256, 2) void k_scores(
    const unsigned short* __restrict__ A, const unsigned short* __restrict__ B,
    const int* __restrict__ tmask, const int* __restrict__ imask,
    float* __restrict__ S, unsigned short* __restrict__ Wh)
{
    union SmemU {
        char  stage[2][32768];     // [buf][A 16KB | B 16KB]
        float Cs[NN][129];         // 66 KB epilogue tile (stride 129: 2-way free)
    };
    __shared__ SmemU u;
    __shared__ float tmi[NN];
    __shared__ float imj[NN];      // 128 cols = two j's
    __shared__ float rowred[256];
    __shared__ float colred[NN];
    __shared__ float rowm[256], rowsm[256];          // phase-1 row stats stash
    __shared__ float colm[256], colp1[256], colp2[256];  // phase-2 partials

    // 4x4 block-group swizzle for L2 locality (~1.6 MB working set / group)
    const int bid = blockIdx.x;
    const int grp = bid >> 4, idx = bid & 15;
    const int i  = (grp >> 3) * 4 + (idx >> 2);   // 0..63
    const int jj = (grp & 7) * 4 + (idx & 3);     // 0..31
    const int j0 = jj * 2;

    const int tid  = threadIdx.x;
    const int wave = tid >> 6;
    const int lane = tid & 63;
    const int quad = lane >> 4;
    const int l15  = lane & 15;
    const int rh   = wave & 1;     // row half (64 rows)
    const int ch   = wave >> 1;    // col half (64 cols)

    if (tid < NN) {
        tmi[tid] = tmask[i * NN + tid] ? 1.f : 0.f;
        imj[tid] = imask[j0 * LL + tid] ? 1.f : 0.f;   // two j's contiguous
    }

    const unsigned short* pa = A + (size_t)i * NN * DD;
    const unsigned short* pb = B + (size_t)j0 * LL * DD;

    f32x4 acc[4][4];
    const f32x4 zf = {0.f, 0.f, 0.f, 0.f};
#pragma unroll
    for (int tr = 0; tr < 4; tr++)
#pragma unroll
        for (int tc = 0; tc < 4; tc++) acc[tr][tc] = zf;

    stage_chunk(pa, pb, 0, u.stage[0], wave, lane);
    __syncthreads();

    for (int c = 0; c < 12; c++) {
        if (c + 1 < 12)
            stage_chunk(pa, pb, (c + 1) << 6, u.stage[(c + 1) & 1], wave, lane);
        const char* Ab = u.stage[c & 1];
        const char* Bb = Ab + 16384;
#pragma unroll
        for (int s = 0; s < 2; s++) {
            int k8q = s * 4 + quad;
            int sw  = k8q ^ (l15 & 7);
            f16x8 af[4], bfr[4];
#pragma unroll
            for (int t = 0; t < 4; t++) {
                int row = rh * 64 + t * 16 + l15;
                af[t]  = *(const f16x8*)(Ab + ((row << 3) + sw) * 16);
                int col = ch * 64 + t * 16 + l15;
                bfr[t] = *(const f16x8*)(Bb + ((col << 3) + sw) * 16);
            }
#pragma unroll
            for (int tr = 0; tr < 4; tr++)
#pragma unroll
                for (int tc = 0; tc < 4; tc++)
                    acc[tr][tc] = __builtin_amdgcn_mfma_f32_16x16x32_f16(
                        af[tr], bfr[tc], acc[tr][tc], 0, 0, 0);
        }
        __syncthreads();
    }

    // masked att -> Cs.  att = (mask && dot != 0) ? dot : NEG
    // C/D layout per 16x16 tile: row = quad*4 + rr, col = l15
#pragma unroll
    for (int tr = 0; tr < 4; tr++) {
        int rb = rh * 64 + tr * 16 + quad * 4;
#pragma unroll
        for (int tc = 0; tc < 4; tc++) {
            int col = ch * 64 + tc * 16 + l15;
            float im = imj[col];
#pragma unroll
            for (int rr = 0; rr < 4; rr++) {
                int row = rb + rr;
                float v = acc[tr][tc][rr];
                bool keep = (tmi[row] != 0.f) && (im != 0.f) && (v != 0.f);
                u.Cs[row][col] = keep ? v : NEGV;
            }
        }
    }
    __syncthreads();

    // phase 1: row softmax over l for each (jh, n) -- all 256 threads
    {
        int jh = tid >> 7, n = tid & 127;
        const float* Crow = &u.Cs[n][jh * 64];
        float m = -INFINITY;
        for (int l = 0; l < LL; l++) m = fmaxf(m, Crow[l]);
        float ssum = 0.f, ws = 0.f;
        for (int l = 0; l < LL; l++) {
            float v = Crow[l];
            float e = __expf(v - m);      // all-NEG row -> uniform
            ssum += e;
            ws += imj[jh * 64 + l] * e * v;
        }
        rowm[tid] = m;                    // stash for diagonal W (bit-exact)
        rowsm[tid] = ssum;
        rowred[tid] = tmi[n] * (ws / ssum);
    }
    __syncthreads();

    // phase 2: col softmax, ALL 256 threads, 2 per column (split over n-halves)
    {
        int c  = tid & 127;              // column 0..127
        int n0 = (tid >> 7) * 64;        // row half start
        float m = -INFINITY;
        for (int n = n0; n < n0 + 64; n++) m = fmaxf(m, u.Cs[n][c]);
        colm[tid] = m;
        __syncthreads();
        m = fmaxf(colm[tid], colm[tid ^ 128]);
        float ssum = 0.f, ws = 0.f;
        for (int n = n0; n < n0 + 64; n++) {
            float v = u.Cs[n][c];
            float e = __expf(v - m);
            ssum += e;
            ws += tmi[n] * e * v;
        }
        colp1[tid] = ssum;
        colp2[tid] = ws;
    }
    __syncthreads();
    if (tid < NN) {
        float ssum = colp1[tid] + colp1[tid + 128];
        float ws   = colp2[tid] + colp2[tid + 128];
        colred[tid] = imj[tid] * (ws / ssum);
    }

    // diagonal W (32/2048 blocks): Wh[i][n][l] = fp16(exp(vm - m)/ssum),
    // reusing phase-1 stats (bit-exact P, then RTN to fp16).
    if (jj == (i >> 1) && tid < NN) {
        int jh = i & 1;
        int n = tid;
        float m   = rowm[jh * 128 + n];
        float inv = 1.f / rowsm[jh * 128 + n];
        const float* Crow = &u.Cs[n][jh * 64];
        unsigned short* Wb = Wh + (size_t)i * NN * LL + (size_t)n * LL;
        for (int l = 0; l < LL; l++) {
            _Float16 h = (_Float16)(__expf(Crow[l] - m) * inv);
            Wb[l] = __builtin_bit_cast(unsigned short, h);
        }
    }
    __syncthreads();

    // S[i][j0+jh] = (sum_n rowred + sum_l colred) / N   (waves 0,1)
    if (tid < NN) {
        int jh = tid >> 6, t = tid & 63;
        float p = rowred[jh * 128 + t] + rowred[jh * 128 + 64 + t] + colred[jh * 64 + t];
#pragma unroll
        for (int off = 32; off; off >>= 1) p += __shfl_down(p, off);
        if (t == 0) S[i * BSZ + j0 + jh] = p / (float)NN;
    }
}

// ---------------------------------------------------------------------------
// Kernel 1.5 (R12): transpose fp16 img B [b][l][d] -> B_T [b][d][l]
// (k-contiguous B-operand for the MFMA k_i2s).  Grid (64, 6): 128-d chunks.
// B_T lands in the A region (text fp16 is dead after k_scores).
// ---------------------------------------------------------------------------
__global__ __launch_bounds__(256) void k_tr(
    const unsigned short* __restrict__ B, unsigned short* __restrict__ BT)
{
    __shared__ unsigned short Ls[64][136];   // pad 136: 16B-aligned rows
    const int b  = blockIdx.x;
    const int dc = blockIdx.y;               // 0..5
    const unsigned short* Bb = B + (size_t)b * LL * DD + dc * 128;
#pragma unroll
    for (int rep = 0; rep < 4; rep++) {
        int idx = rep * 256 + threadIdx.x;   // 0..1023
        int l = idx >> 4, d8 = (idx & 15) * 8;
        ushort4 v0 = *(const ushort4*)(Bb + (size_t)l * DD + d8);
        ushort4 v1 = *(const ushort4*)(Bb + (size_t)l * DD + d8 + 4);
        *(ushort4*)(&Ls[l][d8])     = v0;
        *(ushort4*)(&Ls[l][d8 + 4]) = v1;
    }
    __syncthreads();
    unsigned short* BTb = BT + (size_t)b * DD * LL + (size_t)dc * 128 * LL;
#pragma unroll
    for (int rep = 0; rep < 4; rep++) {
        int idx = rep * 256 + threadIdx.x;   // 0..1023
        int d = idx >> 3, l0 = (idx & 7) * 8;
        ushort4 lo, hi;
        lo.x = Ls[l0 + 0][d]; lo.y = Ls[l0 + 1][d];
        lo.z = Ls[l0 + 2][d]; lo.w = Ls[l0 + 3][d];
        hi.x = Ls[l0 + 4][d]; hi.y = Ls[l0 + 5][d];
        hi.z = Ls[l0 + 6][d]; hi.w = Ls[l0 + 7][d];
        *(ushort4*)(BTb + (size_t)d * LL + l0)     = lo;
        *(ushort4*)(BTb + (size_t)d * LL + l0 + 4) = hi;
    }
}

// ---------------------------------------------------------------------------
// Kernel 2 (R12): MFMA i2s.  out[b,n,d] = sum_l P[l,n] * img[l,d] as f16
// GEMM (M=128 n, N=768 d, K=64 l) per b.  Grid (64, 6): block = 128 n x
// 128 d; 4 waves = 2 n-halves x 2 d-halves, 64x64/wave = acc[4][4] (proven
// 64-reg budget).  A = Wh[n][l], B = B_T[d][l]: both k-contiguous -> direct
// global f16x8 loads, NO LDS.  C/D layout session-verified.
// Old scalar k_i2s was ~76-88 us (LDS-broadcast FMA at 1.5 waves/SIMD);
// this is ~40 MB traffic + 12K wave-MFMAs => ~10 us theory.
// k_loss fused into the tail of block (0,0).
// ---------------------------------------------------------------------------
__global__ __launch_bounds__(256) void k_i2s(
    const unsigned short* __restrict__ Wh, const unsigned short* __restrict__ BT,
    const float* __restrict__ S, float* __restrict__ out)
{
    const int b   = blockIdx.x;
    const int dc  = blockIdx.y;              // 0..5
    const int tid = threadIdx.x;
    const int wave = tid >> 6, lane = tid & 63;
    const int quad = lane >> 4, l15 = lane & 15;
    const int nb = (wave >> 1) * 64;                 // n-base (0 or 64)
    const int db = dc * 128 + (wave & 1) * 64;       // d-base

    const unsigned short* Wb = Wh + (size_t)b * NN * LL;
    const unsigned short* Bb = BT + (size_t)b * DD * LL;

    f32x4 acc[4][4];
    const f32x4 zf = {0.f, 0.f, 0.f, 0.f};
#pragma unroll
    for (int tn = 0; tn < 4; tn++)
#pragma unroll
        for (int td = 0; td < 4; td++) acc[tn][td] = zf;

#pragma unroll
    for (int s = 0; s < 2; s++) {
        f16x8 af[4], bf[4];
#pragma unroll
        for (int t = 0; t < 4; t++) {
            af[t] = *(const f16x8*)(Wb + (size_t)(nb + t * 16 + l15) * LL + s * 32 + quad * 8);
            bf[t] = *(const f16x8*)(Bb + (size_t)(db + t * 16 + l15) * LL + s * 32 + quad * 8);
        }
#pragma unroll
        for (int tn = 0; tn < 4; tn++)
#pragma unroll
            for (int td = 0; td < 4; td++)
                acc[tn][td] = __builtin_amdgcn_mfma_f32_16x16x32_f16(
                    af[tn], bf[td], acc[tn][td], 0, 0, 0);
    }

    // C/D: row(n) = quad*4 + rr, col(d) = l15 — coalesced 16-lane stores
    float* ob = out + 1 + (size_t)b * NN * DD;
#pragma unroll
    for (int tn = 0; tn < 4; tn++)
#pragma unroll
        for (int td = 0; td < 4; td++)
#pragma unroll
            for (int rr = 0; rr < 4; rr++) {
                int n = nb + tn * 16 + quad * 4 + rr;
                int d = db + td * 16 + l15;
                ob[(size_t)n * DD + d] = acc[tn][td][rr];
            }

    // fused loss: loss = -sum_i( 2*S[i,i] - lse_row_i(S) - lse_col_i(S) ) / B
    if (blockIdx.x == 0 && blockIdx.y == 0 && tid < 64) {
        const int t = tid;  // 0..63
        float diag = S[t * BSZ + t];
        float m1 = -INFINITY, m2 = -INFINITY;
        for (int jj = 0; jj < BSZ; jj++) {
            m1 = fmaxf(m1, S[t * BSZ + jj]);
            m2 = fmaxf(m2, S[jj * BSZ + t]);
        }
        float s1 = 0.f, s2 = 0.f;
        for (int jj = 0; jj < BSZ; jj++) {
            s1 += __expf(S[t * BSZ + jj] - m1);
            s2 += __expf(S[jj * BSZ + t] - m2);
        }
        float p = 2.f * diag - (m1 + logf(s1)) - (m2 + logf(s2));
#pragma unroll
        for (int off = 32; off; off >>= 1) p += __shfl_down(p, off);
        if (t == 0) out[0] = -p / (float)BSZ;
    }
}

// ---------------------------------------------------------------------------
extern "C" void kernel_launch(void* const* d_in, const int* in_sizes, int n_in,
                              void* d_out, int out_size, void* d_ws, size_t ws_size,
                              hipStream_t stream)
{
    (void)in_sizes; (void)n_in; (void)out_size; (void)ws_size;
    const float* text = (const float*)d_in[0];   // [64,128,768] fp32
    const float* img  = (const float*)d_in[1];   // [64, 64,768] fp32
    const int*   tm   = (const int*)d_in[2];     // [64,128] int32
    const int*   im   = (const int*)d_in[3];     // [64, 64] int32
    float* out = (float*)d_out;                  // [1 + 64*128*768] fp32

    // workspace layout (bytes); ~21 MB total (unchanged):
    //   A  [0, 12.58M)        text fp16; REUSED as B_T [b][d][l] after k_scores
    //   B  [12.58M, 18.87M)   image fp16 [b][l][d]
    //   S  at 18874368        16 KB
    //   Wh at 18890752        1.05 MB fp16 P^T [i][n][l]
    char* ws = (char*)d_ws;
    unsigned short* A  = (unsigned short*)(ws);
    unsigned short* B  = (unsigned short*)(ws + 12582912);
    float*          S  = (float*)(ws + 18874368);
    unsigned short* Wh = (unsigned short*)(ws + 18890752);
    unsigned short* BT = A;   // A is dead after k_scores

    k_prep<<<(TQ + IQ) / 256, 256, 0, stream>>>(
        (const float4*)text, (const float4*)img, (ushort4*)A, (ushort4*)B);

    k_scores<<<BSZ * (BSZ / 2), 256, 0, stream>>>(A, B, tm, im, S, Wh);

    dim3 gt(BSZ, 6);
    k_tr<<<gt, 256, 0, stream>>>(B, BT);

    dim3 g2(BSZ, 6);
    k_i2s<<<g2, 256, 0, stream>>>(Wh, BT, S, out);
}